// Round 7
// baseline (1693.096 us; speedup 1.0000x reference)
//
#include <hip/hip_runtime.h>
#include <math.h>

#define Bsz 1024
#define Hd  256
#define MAXTILE 40               // max row-tiles per cell (worst case: 9 buckets -> exactly 40)
#define PERM_PER_CELL (MAXTILE*32)
#define WCSTRIDE (512*768)       // one combo matrix: [W1c | W2c | Wm], k=512 x 768 cols
#define GHALF (Bsz*768)          // one split-k partial buffer
#define NPART 4                  // split-k partials (2 per neighbor half)

// ---------- build 16 combined weight matrices: Wc[a*4+b] --------------------
// col<256:   (a<3 ? W1[a] : 0) + (b<3 ? W1[3+b] : 0)   [:, col]
// col<512:   same with W2                               [:, col-256]
// col>=512:  Wmerge[:, col-512]                         (combo-independent)
__global__ __launch_bounds__(256)
void build_wc(const float* __restrict__ W1, const float* __restrict__ W2,
              const float* __restrict__ Wm, float* __restrict__ Wc)
{
    size_t idx = (size_t)blockIdx.x * 256 + threadIdx.x;   // < 16*512*768
    int col = (int)(idx % 768);
    size_t rem = idx / 768;
    int j = (int)(rem % 512);
    int c = (int)(rem / 512);
    int a = c >> 2, b = c & 3;
    float v;
    if (col < 256) {
        v = ((a < 3) ? W1[(size_t)a * 512 * 256 + j * 256 + col] : 0.f)
          + ((b < 3) ? W1[(size_t)(3 + b) * 512 * 256 + j * 256 + col] : 0.f);
    } else if (col < 512) {
        int cc = col - 256;
        v = ((a < 3) ? W2[(size_t)a * 512 * 256 + j * 256 + cc] : 0.f)
          + ((b < 3) ? W2[(size_t)(3 + b) * 512 * 256 + j * 256 + cc] : 0.f);
    } else {
        v = Wm[(size_t)j * 256 + (col - 512)];
    }
    Wc[idx] = v;
}

// ---------- bucketize: per cell, sort sample indices by combo ---------------
// one block per cell (64 blocks x 256 threads); cell index is snake-order
__global__ __launch_bounds__(256)
void bucketize(const int* __restrict__ samples, int* __restrict__ perm,
               int* __restrict__ tiletab)
{
    const int cell = blockIdx.x;         // 0..63 in snake order
    const int t = threadIdx.x;
    const int ny = cell >> 3, ixs = cell & 7;
    const int nx  = (ny & 1) ? (7 - ixs) : ixs;
    const int dx  = (ny & 1) ? 1 : -1;
    const int nxn = nx + dx;
    const bool hasX = (nxn >= 0) && (nxn < 8);
    const bool hasY = (ny > 0);
    const int sx_off = nxn * 8 + ny;
    const int sy_off = nx * 8 + ny - 1;

    __shared__ int hist[16], cursor[16];
    int* pcell = perm + (size_t)cell * PERM_PER_CELL;
    for (int i = t; i < PERM_PER_CELL; i += 256) pcell[i] = -1;
    if (t < 16) hist[t] = 0;
    __syncthreads();

    int myc[4];
#pragma unroll
    for (int q = 0; q < 4; q++) {
        int l = t * 4 + q;
        int a = hasX ? samples[l * 64 + sx_off] : 3;
        int b = hasY ? samples[l * 64 + sy_off] : 3;
        myc[q] = a * 4 + b;
        atomicAdd(&hist[myc[q]], 1);
    }
    __syncthreads();

    if (t == 0) {
        int tile = 0, row = 0;
        for (int c = 0; c < 16; c++) {
            cursor[c] = row;
            int nt = (hist[c] + 31) >> 5;
            for (int k = 0; k < nt; k++) tiletab[cell * MAXTILE + tile + k] = c;
            tile += nt;
            row  += nt * 32;
        }
        for (; tile < MAXTILE; tile++) tiletab[cell * MAXTILE + tile] = -1;
    }
    __syncthreads();

#pragma unroll
    for (int q = 0; q < 4; q++) {
        int l = t * 4 + q;
        int pos = atomicAdd(&cursor[myc[q]], 1);
        pcell[pos] = l;
    }
}

// ---------------- per-cell bucketed split-k GEMM ----------------------------
// chunk z covers absolute k in [z*128, z*128+128) clipped to [kbeg, kend):
//   z=0,1 read hx (h-index = k), z=2,3 read hy (h-index = k-256)
// Gp[z][l,:] = partial; absent range -> zeros (combine always sums all 4)
// grid: (12 col-tiles of 64, MAXTILE row-tiles of 32, 4 chunks), 128 threads
#define BM 32
#define BN 64
#define BKt 32

__global__ __launch_bounds__(128)
void gemm_cell(const float* __restrict__ hx, const float* __restrict__ hy,
               const float* __restrict__ Wc, const int* __restrict__ perm,
               const int* __restrict__ tiletab, float* __restrict__ Gp,
               int cell, int kbeg, int kend)
{
    const int combo = tiletab[cell * MAXTILE + blockIdx.y];
    if (combo < 0) return;                         // block-uniform exit
    const int chunk = blockIdx.z;                  // 0..3
    const int kbase = chunk << 7;                  // 0,128,256,384
    const int hoff  = (chunk < 2) ? 0 : 256;       // h-index = k - hoff
    int lo = (kbeg > kbase) ? kbeg : kbase;
    int hi = kbase + 128; if (kend < hi) hi = kend;
    const float* hsrc = (chunk < 2) ? hx : hy;     // null only when range empty
    const int k0 = blockIdx.x * BN;
    const float* Wsrc = Wc + (size_t)combo * WCSTRIDE;
    const int* pr = perm + (size_t)cell * PERM_PER_CELL + blockIdx.y * BM;
    float* Gout = Gp + (size_t)chunk * GHALF;

    const int t  = threadIdx.x;
    const int ar = t >> 2;               // 0..31 A row
    const int aj = (t & 3) * 8;          // 0,8,16,24
    const int bj = t >> 4;               // 0..7  B row (+8,+16,+24)
    const int bc = (t & 15) * 4;         // 0..60 B col-quad
    const int ty = t >> 4;               // 0..7  compute row group (x4)
    const int tx = t & 15;               // 0..15 compute col group (x4)

    __shared__ float As[BKt][BM];        // 4 KB
    __shared__ float Bs[BKt][BN];        // 8 KB
    __shared__ int rowidx[BM];
    if (t < BM) rowidx[t] = pr[t];
    const int myrow = pr[ar];

    float acc[4][4];
#pragma unroll
    for (int i = 0; i < 4; i++)
#pragma unroll
        for (int j = 0; j < 4; j++) acc[i][j] = 0.0f;

    for (int kk = lo; kk < hi; kk += BKt) {
        float4 a0 = make_float4(0.f, 0.f, 0.f, 0.f), a1 = a0;
        if (myrow >= 0) {
            const float* ap = hsrc + (size_t)myrow * Hd + (kk - hoff) + aj;
            a0 = *reinterpret_cast<const float4*>(ap);
            a1 = *reinterpret_cast<const float4*>(ap + 4);
        }
        const float* bp = Wsrc + (size_t)(kk + bj) * 768 + k0 + bc;
        float4 b0 = *reinterpret_cast<const float4*>(bp);
        float4 b1 = *reinterpret_cast<const float4*>(bp +  8 * 768);
        float4 b2 = *reinterpret_cast<const float4*>(bp + 16 * 768);
        float4 b3 = *reinterpret_cast<const float4*>(bp + 24 * 768);

        __syncthreads();    // previous tile fully consumed
        As[aj + 0][ar] = a0.x; As[aj + 1][ar] = a0.y;
        As[aj + 2][ar] = a0.z; As[aj + 3][ar] = a0.w;
        As[aj + 4][ar] = a1.x; As[aj + 5][ar] = a1.y;
        As[aj + 6][ar] = a1.z; As[aj + 7][ar] = a1.w;
        *reinterpret_cast<float4*>(&Bs[bj     ][bc]) = b0;
        *reinterpret_cast<float4*>(&Bs[bj +  8][bc]) = b1;
        *reinterpret_cast<float4*>(&Bs[bj + 16][bc]) = b2;
        *reinterpret_cast<float4*>(&Bs[bj + 24][bc]) = b3;
        __syncthreads();

#pragma unroll
        for (int j = 0; j < BKt; j++) {
            float4 a = *reinterpret_cast<const float4*>(&As[j][ty * 4]);
            float4 b = *reinterpret_cast<const float4*>(&Bs[j][tx * 4]);
            float aa[4] = {a.x, a.y, a.z, a.w};
            float bb[4] = {b.x, b.y, b.z, b.w};
#pragma unroll
            for (int i = 0; i < 4; i++)
#pragma unroll
                for (int jj = 0; jj < 4; jj++)
                    acc[i][jj] = fmaf(aa[i], bb[jj], acc[i][jj]);
        }
    }
    __syncthreads();   // covers rowidx write->read (also when k-range empty)

#pragma unroll
    for (int i = 0; i < 4; i++) {
        int r = rowidx[ty * 4 + i];
        if (r >= 0) {
            float* gp = Gout + (size_t)r * 768 + k0 + tx * 4;
            float4 o = {acc[i][0], acc[i][1], acc[i][2], acc[i][3]};
            *reinterpret_cast<float4*>(gp) = o;
        }
    }
}

// ------- fused per-cell combine (GRU nonlinearity) + log-prob update --------
// Gp row layout per chunk: [0:256)=pre1, [256:512)=pre2, [512:768)=merge
// kcell==0 bootstraps accumulators (no init kernel); kcell==63 writes d_out.
// grid: 1024 blocks (one per sample) x 256 threads (one per hidden unit)
__global__ __launch_bounds__(256)
void combine_logprob(const float* __restrict__ Gp, const int* __restrict__ samples,
                     const float* __restrict__ b1, const float* __restrict__ b2,
                     const float* __restrict__ Wl1, const float* __restrict__ bl1,
                     const float* __restrict__ Wl2, const float* __restrict__ bl2,
                     float* __restrict__ hout, float* __restrict__ acc,
                     float* __restrict__ out, int s_off, int kcell)
{
    const int l = blockIdx.x;
    const int k = threadIdx.x;
    const float* g0 = Gp + (size_t)l * 768;

    float pre1 = b1[k], pre2 = b2[k], mg = 0.f;
#pragma unroll
    for (int z = 0; z < NPART; z++) {
        const float* g = g0 + (size_t)z * GHALF;
        pre1 += g[k];
        pre2 += g[256 + k];
        mg   += g[512 + k];
    }
    float ht = tanhf(pre1);
    float u  = 1.0f / (1.0f + expf(-pre2));
    float h  = u * ht + (1.0f - u) * mg;
    hout[(size_t)l * Hd + k] = h;

    // readout dot products: p1[i] = h . Wl1[:,i], p2[i] = h . Wl2[:,i]
    float v[6];
    v[0] = h * Wl1[k * 3 + 0];
    v[1] = h * Wl1[k * 3 + 1];
    v[2] = h * Wl1[k * 3 + 2];
    v[3] = h * Wl2[k * 3 + 0];
    v[4] = h * Wl2[k * 3 + 1];
    v[5] = h * Wl2[k * 3 + 2];
#pragma unroll
    for (int m = 1; m < 64; m <<= 1)
#pragma unroll
        for (int i = 0; i < 6; i++) v[i] += __shfl_xor(v[i], m);

    __shared__ float red[4][6];
    if ((k & 63) == 0) {
#pragma unroll
        for (int i = 0; i < 6; i++) red[k >> 6][i] = v[i];
    }
    __syncthreads();

    if (k == 0) {
        float p1[3], p2[3];
#pragma unroll
        for (int i = 0; i < 3; i++) {
            p1[i] = red[0][i]     + red[1][i]     + red[2][i]     + red[3][i];
            p2[i] = red[0][3 + i] + red[1][3 + i] + red[2][3 + i] + red[3][3 + i];
        }
        float la, lp, nu, nd;
        if (kcell == 0) { la = 0.f; lp = 0.f; nu = 0.f; nd = 0.f; }
        else {
            la = acc[l];           lp = acc[Bsz + l];
            nu = acc[2 * Bsz + l]; nd = acc[3 * Bsz + l];
        }
        // stable softmax over 3 logits
        float z0 = p1[0] + bl1[0], z1 = p1[1] + bl1[1], z2 = p1[2] + bl1[2];
        float zm = fmaxf(z0, fmaxf(z1, z2));
        float e0 = expf(z0 - zm), e1 = expf(z1 - zm), e2 = expf(z2 - zm);
        float es = e0 + e1 + e2;
        // masks use pre-update counters; bl_up=bl_dn=24, bl_hole=16
        float mh = (16.0f - ((float)kcell - nu - nd) > 0.0f) ? 1.0f : 0.0f;
        float md = (24.0f - nd > 0.0f) ? 1.0f : 0.0f;
        float mu = (24.0f - nu > 0.0f) ? 1.0f : 0.0f;
        float a0 = (e0 / es) * mh, a1 = (e1 / es) * md, a2 = (e2 / es) * mu;
        float asum = fmaxf(a0 + a1 + a2, 1e-30f);
        int sv = samples[l * 64 + s_off];
        float av = ((sv == 0) ? a0 : (sv == 1) ? a1 : a2) / asum;
        float q  = p2[sv] + bl2[sv];
        float ph = 3.14159265358979323846f * (q / (1.0f + fabsf(q)));
        la += logf(fmaxf(av, 1e-12f));
        lp += ph;
        nu += (sv == 2) ? 1.0f : 0.0f;
        nd += (sv == 1) ? 1.0f : 0.0f;
        acc[l] = la; acc[Bsz + l] = lp;
        acc[2 * Bsz + l] = nu; acc[3 * Bsz + l] = nd;
        if (kcell == 63) {           // final cell: emit outputs directly
            out[l]       = 0.5f * la;
            out[Bsz + l] = lp;
        }
    }
}

// ---------------------------------------------------------------------------
extern "C" void kernel_launch(void* const* d_in, const int* in_sizes, int n_in,
                              void* d_out, int out_size, void* d_ws, size_t ws_size,
                              hipStream_t stream)
{
    const int*   samples = (const int*)  d_in[0];
    const float* W1  = (const float*)d_in[1];
    const float* b1  = (const float*)d_in[2];
    const float* W2  = (const float*)d_in[3];
    const float* b2  = (const float*)d_in[4];
    const float* Wm  = (const float*)d_in[5];
    const float* Wl1 = (const float*)d_in[6];
    const float* bl1 = (const float*)d_in[7];
    const float* Wl2 = (const float*)d_in[8];
    const float* bl2 = (const float*)d_in[9];

    float* ws   = (float*)d_ws;
    float* Hcol = ws;                                     // 8*B*H        = 2,097,152 f
    float* Gp   = Hcol + (size_t)8 * Bsz * Hd;            // NPART*B*768  = 3,145,728 f
    float* acc  = Gp   + (size_t)NPART * GHALF;           // 4*B: log_a, log_p, n_up, n_dn
    float* Wc   = acc  + 4 * Bsz;                         // 16*512*768   = 6,291,456 f
    int*   perm    = (int*)(Wc + (size_t)16 * WCSTRIDE);  // 64*1280 ints
    int*   tiletab = perm + (size_t)64 * PERM_PER_CELL;   // 64*40 ints
    float* out  = (float*)d_out;

    build_wc<<<dim3(16 * 512 * 768 / 256), dim3(256), 0, stream>>>(W1, W2, Wm, Wc);
    bucketize<<<dim3(64), dim3(256), 0, stream>>>(samples, perm, tiletab);

    int kcell = 0;
    for (int ny = 0; ny < 8; ny++) {
        const int x0  = (ny % 2 == 0) ? 0 : 7;
        const int dxs = (ny % 2 == 0) ? 1 : -1;
        const int dx  = (ny % 2 == 0) ? -1 : 1;
        for (int ix = 0; ix < 8; ix++) {
            const int nx  = x0 + ix * dxs;
            const int nxn = nx + dx;
            const bool hasX = (nxn >= 0 && nxn < 8);
            const bool hasY = (ny > 0);
            const float* hx = hasX ? (Hcol + (size_t)nxn * Bsz * Hd) : nullptr;
            const float* hy = hasY ? (Hcol + (size_t)nx  * Bsz * Hd) : nullptr;
            const int kbeg = hasX ? 0   : 256;
            const int kend = hasY ? 512 : 256;

            gemm_cell<<<dim3(12, MAXTILE, NPART), dim3(128), 0, stream>>>(
                hx, hy, Wc, perm, tiletab, Gp, kcell, kbeg, kend);

            combine_logprob<<<dim3(Bsz), dim3(256), 0, stream>>>(
                Gp, samples, b1, b2, Wl1, bl1, Wl2, bl2,
                Hcol + (size_t)nx * Bsz * Hd, acc, out, nx * 8 + ny, kcell);
            kcell++;
        }
    }
}